// Round 7
// baseline (272.860 us; speedup 1.0000x reference)
//
#include <hip/hip_runtime.h>
#include <math.h>

// GAT 2-layer: N=10000, E=160000 (+N self loops), IN=128, H1=8, C1=128, OUT=64.
// R7: l1_gemm = (64-node, head) blocks, 32KB LDS (occupancy), W1h from L2 once
//     per block (80 MB total). l1_aggx stages x rows in LDS per 64-edge chunk
//     (512 B/edge instead of 4 KB/edge).

#define NEG_SLOPE 0.2f

__device__ __forceinline__ float leaky(float v) { return v >= 0.0f ? v : NEG_SLOPE * v; }

// ---------------- CSR build ----------------

__global__ void count_kernel(const int* __restrict__ ei, int* __restrict__ counts, int E, int N) {
    int i = blockIdx.x * blockDim.x + threadIdx.x;
    int M = E + N;
    if (i >= M) return;
    int dst = (i < E) ? ei[E + i] : (i - E);   // self-loop tail
    atomicAdd(&counts[dst], 1);
}

__global__ __launch_bounds__(1024) void scan_kernel(
    const int* __restrict__ counts, int* __restrict__ offsets,
    int* __restrict__ cursor, int N) {
    __shared__ int sums[1024];
    int t = threadIdx.x;
    int per = (N + 1023) / 1024;
    int base = t * per;
    int s = 0;
    for (int j = 0; j < per; j++) {
        int idx = base + j;
        if (idx < N) s += counts[idx];
    }
    sums[t] = s;
    __syncthreads();
    int acc = s;
    for (int off = 1; off < 1024; off <<= 1) {
        int v = (t >= off) ? sums[t - off] : 0;
        __syncthreads();
        acc += v;
        sums[t] = acc;
        __syncthreads();
    }
    int run = acc - s;
    for (int j = 0; j < per; j++) {
        int idx = base + j;
        if (idx < N) {
            offsets[idx] = run;
            cursor[idx] = run;
            run += counts[idx];
        }
    }
    if (t == 1023) offsets[N] = run;
}

__global__ void fill_kernel(const int* __restrict__ ei, int* __restrict__ cursor,
                            int* __restrict__ srcs, int E, int N) {
    int i = blockIdx.x * blockDim.x + threadIdx.x;
    int M = E + N;
    if (i >= M) return;
    int src, dst;
    if (i < E) { src = ei[i]; dst = ei[E + i]; }
    else       { src = dst = i - E; }
    int pos = atomicAdd(&cursor[dst], 1);
    srcs[pos] = src;
}

// ---------------- prep: As[k,h] = sum_c W1[k,h*128+c]*a_src1[h,c]  (and Ad) ----

__global__ __launch_bounds__(256) void prep_kernel(
    const float* __restrict__ W1, const float* __restrict__ a_src1,
    const float* __restrict__ a_dst1, float* __restrict__ As, float* __restrict__ Ad) {
    int i = blockIdx.x * 256 + threadIdx.x;   // 0..1023
    int k = i >> 3, h = i & 7;
    float ss = 0.f, sd = 0.f;
    for (int c = 0; c < 128; c += 4) {
        float4 w = *(const float4*)(W1 + (size_t)k * 1024 + h * 128 + c);
        float4 a = *(const float4*)(a_src1 + h * 128 + c);
        float4 d = *(const float4*)(a_dst1 + h * 128 + c);
        ss += w.x * a.x + w.y * a.y + w.z * a.z + w.w * a.w;
        sd += w.x * d.x + w.y * d.y + w.z * d.z + w.w * d.w;
    }
    As[k * 8 + h] = ss;
    Ad[k * 8 + h] = sd;
}

// ---------------- alpha1: as1/ad1 = x @ As / Ad  [N,8] ----------------

__global__ __launch_bounds__(256) void alpha1_kernel(
    const float* __restrict__ x, const float* __restrict__ As, const float* __restrict__ Ad,
    float* __restrict__ as1, float* __restrict__ ad1, int N) {
    __shared__ float sAs[1024], sAd[1024];
    int t = threadIdx.x;
    {
        int i = t * 4;
        *(float4*)(sAs + i) = *(const float4*)(As + i);
        *(float4*)(sAd + i) = *(const float4*)(Ad + i);
    }
    __syncthreads();
    int node = blockIdx.x * 32 + (t >> 3);
    int h = t & 7;
    if (node >= N) return;
    float accs = 0.f, accd = 0.f;
    for (int k = 0; k < 128; k += 4) {
        float4 xv = *(const float4*)(x + (size_t)node * 128 + k);
        accs += xv.x * sAs[k * 8 + h] + xv.y * sAs[(k + 1) * 8 + h]
              + xv.z * sAs[(k + 2) * 8 + h] + xv.w * sAs[(k + 3) * 8 + h];
        accd += xv.x * sAd[k * 8 + h] + xv.y * sAd[(k + 1) * 8 + h]
              + xv.z * sAd[(k + 2) * 8 + h] + xv.w * sAd[(k + 3) * 8 + h];
    }
    as1[node * 8 + h] = accs;
    ad1[node * 8 + h] = accd;
}

// ---------------- l1_aggx: y[n,h,:] = sum_e softmax-w * x[src,:] -----------
// Per 64-edge chunk: stage x rows (32 KB) + weights in LDS once, then all
// 8 head-groups accumulate from LDS broadcasts. Global x traffic: 512 B/edge.

#define ACH 64

__global__ __launch_bounds__(256) void l1_aggx(
    const float* __restrict__ x, const float* __restrict__ as1, const float* __restrict__ ad1,
    const int* __restrict__ offsets, const int* __restrict__ srcs,
    float* __restrict__ y, int N) {
    int n = blockIdx.x;
    int t = threadIdx.x;
    int beg = offsets[n];
    int deg = offsets[n + 1] - beg;
    __shared__ int   ssrc[ACH];
    __shared__ float xs[ACH * 128];   // 32 KB
    __shared__ float wsh[ACH * 8];
    __shared__ float ad[8], mh[8];
    __shared__ float red[256];
    if (t < 8) ad[t] = ad1[n * 8 + t];
    __syncthreads();
    // phase A: per-head max (8 heads x 32 edge-lanes)
    int h8 = t & 7, el = t >> 3;
    float m = -3.4e38f;
    for (int i = el; i < deg; i += 32) {
        int s = srcs[beg + i];
        m = fmaxf(m, leaky(as1[s * 8 + h8] + ad[h8]));
    }
    red[t] = m;
    __syncthreads();
    for (int off = 128; off >= 8; off >>= 1) {
        if (t < off) red[t] = fmaxf(red[t], red[t + off]);
        __syncthreads();
    }
    if (t < 8) mh[t] = red[t];
    __syncthreads();
    // phase B: chunked LDS staging (srcs, x rows, weights) + accumulate
    int h = t >> 5;
    int k0 = (t & 31) * 4;
    int lane5 = t & 31;
    float ax = 0.f, ay = 0.f, az = 0.f, aw = 0.f, ssum = 0.f;
    for (int cb = 0; cb < deg; cb += ACH) {
        int cd = min(ACH, deg - cb);
        if (t < cd) ssrc[t] = srcs[beg + cb + t];
        __syncthreads();
        // stage x rows: 8 row-slots x 32 lanes, 8 passes
#pragma unroll
        for (int r = 0; r < 8; r++) {
            int i = r * 8 + h;   // h doubles as row-slot 0..7
            if (i < cd)
                *(float4*)(xs + i * 128 + lane5 * 4) =
                    *(const float4*)(x + (size_t)ssrc[i] * 128 + lane5 * 4);
        }
        // weights: cd*8 <= 512 entries
        for (int idx = t; idx < cd * 8; idx += 256) {
            int i = idx >> 3, hx = idx & 7;
            int s = ssrc[i];
            wsh[idx] = __expf(leaky(as1[s * 8 + hx] + ad[hx]) - mh[hx]);
        }
        __syncthreads();
        for (int i = 0; i < cd; i++) {
            float w = wsh[i * 8 + h];
            float4 v = *(const float4*)(xs + i * 128 + k0);   // 2-addr broadcast
            ax = fmaf(w, v.x, ax); ay = fmaf(w, v.y, ay);
            az = fmaf(w, v.z, az); aw = fmaf(w, v.w, aw);
            ssum += w;
        }
        __syncthreads();
    }
    float inv = 1.0f / (ssum + 1e-16f);
    *(float4*)(y + (size_t)n * 1024 + t * 4) =
        make_float4(ax * inv, ay * inv, az * inv, aw * inv);
}

// ---------------- l1_gemm: hbuf = ELU(per-head y @ W1h + b1) ----------------
// Block = (64-node tile, head h). LDS: ys 32 KB only. W1h streamed from L2
// (once per block; 1256 x 64 KB = 80 MB total). Thread: c0=(t&31)*4,
// ng=t>>5 -> 8 nodes. Grid = ceil(N/64)*8 = 1256.

__global__ __launch_bounds__(256) void l1_gemm(
    const float* __restrict__ y, const float* __restrict__ W1,
    const float* __restrict__ b1, float* __restrict__ hbuf, int N) {
    int h = blockIdx.x & 7;
    int nb = (blockIdx.x >> 3) * 64;
    int t = threadIdx.x;
    __shared__ float ys[64 * 128];     // 32 KB
#pragma unroll
    for (int r = 0; r < 8; r++) {
        int idx = r * 256 + t;          // float4 index, 2048 total
        int nd = idx >> 5, fq = idx & 31;
        int node = nb + nd;
        float4 v = make_float4(0.f, 0.f, 0.f, 0.f);
        if (node < N) v = *(const float4*)(y + (size_t)node * 1024 + h * 128 + fq * 4);
        *(float4*)(ys + nd * 128 + fq * 4) = v;
    }
    __syncthreads();
    int c0 = (t & 31) * 4;
    int ng = t >> 5;           // nodes ng*8 .. ng*8+7
    float4 acc[8];
#pragma unroll
    for (int nd = 0; nd < 8; nd++) acc[nd] = make_float4(0.f, 0.f, 0.f, 0.f);
    const float* Wc = W1 + h * 128 + c0;
    for (int k = 0; k < 128; k += 4) {
        float4 w0 = *(const float4*)(Wc + (size_t)(k + 0) * 1024);
        float4 w1 = *(const float4*)(Wc + (size_t)(k + 1) * 1024);
        float4 w2 = *(const float4*)(Wc + (size_t)(k + 2) * 1024);
        float4 w3 = *(const float4*)(Wc + (size_t)(k + 3) * 1024);
#pragma unroll
        for (int nd = 0; nd < 8; nd++) {
            float4 yv = *(const float4*)(ys + (ng * 8 + nd) * 128 + k);  // broadcast
            acc[nd].x = fmaf(yv.x, w0.x, acc[nd].x);
            acc[nd].y = fmaf(yv.x, w0.y, acc[nd].y);
            acc[nd].z = fmaf(yv.x, w0.z, acc[nd].z);
            acc[nd].w = fmaf(yv.x, w0.w, acc[nd].w);
            acc[nd].x = fmaf(yv.y, w1.x, acc[nd].x);
            acc[nd].y = fmaf(yv.y, w1.y, acc[nd].y);
            acc[nd].z = fmaf(yv.y, w1.z, acc[nd].z);
            acc[nd].w = fmaf(yv.y, w1.w, acc[nd].w);
            acc[nd].x = fmaf(yv.z, w2.x, acc[nd].x);
            acc[nd].y = fmaf(yv.z, w2.y, acc[nd].y);
            acc[nd].z = fmaf(yv.z, w2.z, acc[nd].z);
            acc[nd].w = fmaf(yv.z, w2.w, acc[nd].w);
            acc[nd].x = fmaf(yv.w, w3.x, acc[nd].x);
            acc[nd].y = fmaf(yv.w, w3.y, acc[nd].y);
            acc[nd].z = fmaf(yv.w, w3.z, acc[nd].z);
            acc[nd].w = fmaf(yv.w, w3.w, acc[nd].w);
        }
    }
    float4 bv = *(const float4*)(b1 + h * 128 + c0);
#pragma unroll
    for (int nd = 0; nd < 8; nd++) {
        int node = nb + ng * 8 + nd;
        if (node >= N) break;
        float ox = acc[nd].x + bv.x;
        float oy = acc[nd].y + bv.y;
        float oz = acc[nd].z + bv.z;
        float ow = acc[nd].w + bv.w;
        ox = ox > 0.f ? ox : expm1f(ox);
        oy = oy > 0.f ? oy : expm1f(oy);
        oz = oz > 0.f ? oz : expm1f(oz);
        ow = ow > 0.f ? ow : expm1f(ow);
        *(float4*)(hbuf + (size_t)node * 1024 + h * 128 + c0) = make_float4(ox, oy, oz, ow);
    }
}

// ---------------- Layer 2 transform: h2 = hbuf @ W2, alpha_s2/alpha_d2 ------
// Split-K: 8 nodes/block, thread = (cg=t&15 -> 4 ch, kb=t>>4 -> 64 k).

__global__ __launch_bounds__(256) void l2_transform(
    const float* __restrict__ hbuf, const float* __restrict__ W2,
    const float* __restrict__ a_src2, const float* __restrict__ a_dst2,
    float* __restrict__ h2, float* __restrict__ as2, float* __restrict__ ad2, int N) {
    int nb = blockIdx.x * 8;
    int t = threadIdx.x;
    __shared__ float hs[8 * 1024];     // 32 KB
    __shared__ float part[16 * 512];   // 32 KB
#pragma unroll
    for (int r = 0; r < 8; r++) {
        int idx = r * 1024 + t * 4;
        int node = nb + (idx >> 10);
        float4 v = make_float4(0.f, 0.f, 0.f, 0.f);
        if (node < N) v = *(const float4*)(hbuf + (size_t)node * 1024 + (idx & 1023));
        *(float4*)(hs + idx) = v;
    }
    __syncthreads();
    int cg = t & 15, kb = t >> 4;
    int c0 = cg * 4;
    int kbase = kb * 64;
    float4 acc[8];
#pragma unroll
    for (int nd = 0; nd < 8; nd++) acc[nd] = make_float4(0.f, 0.f, 0.f, 0.f);
    for (int jj = 0; jj < 64; jj += 4) {
        int k = kbase + ((jj + kb * 16) & 63);   // stagger: <=2-way bank overlap
        float4 w0 = *(const float4*)(W2 + (size_t)(k + 0) * 64 + c0);
        float4 w1 = *(const float4*)(W2 + (size_t)(k + 1) * 64 + c0);
        float4 w2 = *(const float4*)(W2 + (size_t)(k + 2) * 64 + c0);
        float4 w3 = *(const float4*)(W2 + (size_t)(k + 3) * 64 + c0);
#pragma unroll
        for (int nd = 0; nd < 8; nd++) {
            float4 yv = *(const float4*)(hs + nd * 1024 + k);
            acc[nd].x = fmaf(yv.x, w0.x, acc[nd].x);
            acc[nd].y = fmaf(yv.x, w0.y, acc[nd].y);
            acc[nd].z = fmaf(yv.x, w0.z, acc[nd].z);
            acc[nd].w = fmaf(yv.x, w0.w, acc[nd].w);
            acc[nd].x = fmaf(yv.y, w1.x, acc[nd].x);
            acc[nd].y = fmaf(yv.y, w1.y, acc[nd].y);
            acc[nd].z = fmaf(yv.y, w1.z, acc[nd].z);
            acc[nd].w = fmaf(yv.y, w1.w, acc[nd].w);
            acc[nd].x = fmaf(yv.z, w2.x, acc[nd].x);
            acc[nd].y = fmaf(yv.z, w2.y, acc[nd].y);
            acc[nd].z = fmaf(yv.z, w2.z, acc[nd].z);
            acc[nd].w = fmaf(yv.z, w2.w, acc[nd].w);
            acc[nd].x = fmaf(yv.w, w3.x, acc[nd].x);
            acc[nd].y = fmaf(yv.w, w3.y, acc[nd].y);
            acc[nd].z = fmaf(yv.w, w3.z, acc[nd].z);
            acc[nd].w = fmaf(yv.w, w3.w, acc[nd].w);
        }
    }
#pragma unroll
    for (int nd = 0; nd < 8; nd++)
        *(float4*)(part + kb * 512 + nd * 64 + c0) = acc[nd];
    __syncthreads();
#pragma unroll
    for (int r = 0; r < 2; r++) {
        int oi = t + r * 256;            // nd*64 + c2
        float v = 0.f;
#pragma unroll
        for (int k2 = 0; k2 < 16; k2++) v += part[k2 * 512 + oi];
        int nd = oi >> 6, c2 = t & 63;
        int node = nb + nd;
        float ps = v * a_src2[c2];
        float pd = v * a_dst2[c2];
#pragma unroll
        for (int mm = 32; mm >= 1; mm >>= 1) {   // node nd occupies exactly one wave
            ps += __shfl_xor(ps, mm);
            pd += __shfl_xor(pd, mm);
        }
        if (node < N) {
            h2[(size_t)node * 64 + c2] = v;
            if (c2 == 0) { as2[node] = ps; ad2[node] = pd; }
        }
    }
}

// ---------------- Layer 2 aggregate ----------------

#define CHUNK 256

__global__ __launch_bounds__(256) void l2_agg(
    const float* __restrict__ h2, const float* __restrict__ as2, const float* __restrict__ ad2,
    const float* __restrict__ b2, const int* __restrict__ offsets, const int* __restrict__ srcs,
    float* __restrict__ out, int N) {
    int n = blockIdx.x;
    int t = threadIdx.x;
    int beg = offsets[n];
    int deg = offsets[n + 1] - beg;
    __shared__ int   ssrc[CHUNK];
    __shared__ float wsh[CHUNK];
    __shared__ float red[256];
    __shared__ float m_sh, s_sh;
    float adn = ad2[n];
    float m = -3.4e38f;
    for (int i = t; i < deg; i += 256) m = fmaxf(m, leaky(as2[srcs[beg + i]] + adn));
    red[t] = m;
    __syncthreads();
    for (int off = 128; off >= 1; off >>= 1) {
        if (t < off) red[t] = fmaxf(red[t], red[t + off]);
        __syncthreads();
    }
    if (t == 0) m_sh = red[0];
    __syncthreads();
    float mv = m_sh;
    int c = t & 63, eg = t >> 6;
    float acc = 0.f, wpart = 0.f;
    for (int cb = 0; cb < deg; cb += CHUNK) {
        int cd = min(CHUNK, deg - cb);
        if (t < cd) {
            int s = srcs[beg + cb + t];
            ssrc[t] = s;
            float w = __expf(leaky(as2[s] + adn) - mv);
            wsh[t] = w;
            wpart += w;
        }
        __syncthreads();
        for (int i = eg; i < cd; i += 4)
            acc = fmaf(wsh[i], h2[(size_t)ssrc[i] * 64 + c], acc);
        __syncthreads();
    }
    red[t] = wpart;
    __syncthreads();
    for (int off = 128; off >= 1; off >>= 1) {
        if (t < off) red[t] += red[t + off];
        __syncthreads();
    }
    if (t == 0) s_sh = red[0] + 1e-16f;
    __syncthreads();
    float stot = s_sh;
    red[t] = acc;
    __syncthreads();
    if (t < 128) red[t] += red[t + 128];
    __syncthreads();
    if (t < 64) {
        float v = red[t] + red[t + 64];
        out[(size_t)n * 64 + t] = v / stot + b2[t];
    }
}

// ---------------- launch ----------------

static inline size_t align_up(size_t v, size_t a) { return (v + a - 1) / a * a; }

extern "C" void kernel_launch(void* const* d_in, const int* in_sizes, int n_in,
                              void* d_out, int out_size, void* d_ws, size_t ws_size,
                              hipStream_t stream) {
    const float* x      = (const float*)d_in[0];
    const int*   ei     = (const int*)d_in[1];
    const float* W1     = (const float*)d_in[2];
    const float* a_src1 = (const float*)d_in[3];
    const float* a_dst1 = (const float*)d_in[4];
    const float* b1     = (const float*)d_in[5];
    const float* W2     = (const float*)d_in[6];
    const float* a_src2 = (const float*)d_in[7];
    const float* a_dst2 = (const float*)d_in[8];
    const float* b2     = (const float*)d_in[9];
    float* out = (float*)d_out;

    int N = in_sizes[0] / 128;
    int E = in_sizes[1] / 2;
    int M = E + N;

    char* p = (char*)d_ws;
    size_t off = 0;
    auto carve = [&](size_t bytes) {
        void* r = p + off;
        off = align_up(off + bytes, 256);
        return r;
    };
    int*   counts  = (int*)carve((size_t)N * 4);
    int*   offsets = (int*)carve((size_t)(N + 1) * 4);
    int*   cursor  = (int*)carve((size_t)N * 4);
    int*   srcs    = (int*)carve((size_t)M * 4);
    float* As      = (float*)carve(1024 * 4);
    float* Ad      = (float*)carve(1024 * 4);
    float* as1     = (float*)carve((size_t)N * 8 * 4);
    float* ad1     = (float*)carve((size_t)N * 8 * 4);
    float* as2     = (float*)carve((size_t)N * 4);
    float* ad2     = (float*)carve((size_t)N * 4);
    float* h2      = (float*)carve((size_t)N * 64 * 4);
    float* y       = (float*)carve((size_t)N * 1024 * 4);
    float* hbuf    = (float*)carve((size_t)N * 1024 * 4);
    (void)ws_size; // ~86 MB

    hipMemsetAsync(counts, 0, (size_t)N * 4, stream);
    prep_kernel<<<4, 256, 0, stream>>>(W1, a_src1, a_dst1, As, Ad);
    alpha1_kernel<<<(N + 31) / 32, 256, 0, stream>>>(x, As, Ad, as1, ad1, N);
    count_kernel<<<(M + 255) / 256, 256, 0, stream>>>(ei, counts, E, N);
    scan_kernel<<<1, 1024, 0, stream>>>(counts, offsets, cursor, N);
    fill_kernel<<<(M + 255) / 256, 256, 0, stream>>>(ei, cursor, srcs, E, N);
    l1_aggx<<<N, 256, 0, stream>>>(x, as1, ad1, offsets, srcs, y, N);
    l1_gemm<<<((N + 63) / 64) * 8, 256, 0, stream>>>(y, W1, b1, hbuf, N);
    l2_transform<<<(N + 7) / 8, 256, 0, stream>>>(hbuf, W2, a_src2, a_dst2, h2, as2, ad2, N);
    l2_agg<<<N, 256, 0, stream>>>(h2, as2, ad2, b2, offsets, srcs, out, N);
}

// Round 8
// 248.768 us; speedup vs baseline: 1.0968x; 1.0968x over previous
//
#include <hip/hip_runtime.h>
#include <math.h>

// GAT 2-layer: N=10000, E=160000 (+N self loops), IN=128, H1=8, C1=128, OUT=64.
// R8: both dense GEMMs moved to bf16 MFMA (16x16x32, fp32 accumulate).
//   - prep transposes W1 -> W1bT [h][c][k] bf16, W2 -> W2bT [c][k] bf16
//   - l1_aggx writes y in bf16
//   - l1_gemm / l2_transform: LDS-free MFMA, A/B frags as 16B global loads
//   Softmax/logit path stays fp32-exact.

#define NEG_SLOPE 0.2f

typedef short bf16x8 __attribute__((ext_vector_type(8)));
typedef float f32x4 __attribute__((ext_vector_type(4)));

__device__ __forceinline__ float leaky(float v) { return v >= 0.0f ? v : NEG_SLOPE * v; }

__device__ __forceinline__ unsigned short f2bf(float f) {
    unsigned u = __float_as_uint(f);
    u += 0x7FFFu + ((u >> 16) & 1u);   // round-to-nearest-even
    return (unsigned short)(u >> 16);
}

// ---------------- CSR build ----------------

__global__ void count_kernel(const int* __restrict__ ei, int* __restrict__ counts, int E, int N) {
    int i = blockIdx.x * blockDim.x + threadIdx.x;
    int M = E + N;
    if (i >= M) return;
    int dst = (i < E) ? ei[E + i] : (i - E);   // self-loop tail
    atomicAdd(&counts[dst], 1);
}

__global__ __launch_bounds__(1024) void scan_kernel(
    const int* __restrict__ counts, int* __restrict__ offsets,
    int* __restrict__ cursor, int N) {
    __shared__ int sums[1024];
    int t = threadIdx.x;
    int per = (N + 1023) / 1024;
    int base = t * per;
    int s = 0;
    for (int j = 0; j < per; j++) {
        int idx = base + j;
        if (idx < N) s += counts[idx];
    }
    sums[t] = s;
    __syncthreads();
    int acc = s;
    for (int off = 1; off < 1024; off <<= 1) {
        int v = (t >= off) ? sums[t - off] : 0;
        __syncthreads();
        acc += v;
        sums[t] = acc;
        __syncthreads();
    }
    int run = acc - s;
    for (int j = 0; j < per; j++) {
        int idx = base + j;
        if (idx < N) {
            offsets[idx] = run;
            cursor[idx] = run;
            run += counts[idx];
        }
    }
    if (t == 1023) offsets[N] = run;
}

__global__ void fill_kernel(const int* __restrict__ ei, int* __restrict__ cursor,
                            int* __restrict__ srcs, int E, int N) {
    int i = blockIdx.x * blockDim.x + threadIdx.x;
    int M = E + N;
    if (i >= M) return;
    int src, dst;
    if (i < E) { src = ei[i]; dst = ei[E + i]; }
    else       { src = dst = i - E; }
    int pos = atomicAdd(&cursor[dst], 1);
    srcs[pos] = src;
}

// ---------------- prep: As[k,h] = sum_c W1[k,h*128+c]*a_src1[h,c]  (and Ad) ----

__global__ __launch_bounds__(256) void prep_kernel(
    const float* __restrict__ W1, const float* __restrict__ a_src1,
    const float* __restrict__ a_dst1, float* __restrict__ As, float* __restrict__ Ad) {
    int i = blockIdx.x * 256 + threadIdx.x;   // 0..1023
    int k = i >> 3, h = i & 7;
    float ss = 0.f, sd = 0.f;
    for (int c = 0; c < 128; c += 4) {
        float4 w = *(const float4*)(W1 + (size_t)k * 1024 + h * 128 + c);
        float4 a = *(const float4*)(a_src1 + h * 128 + c);
        float4 d = *(const float4*)(a_dst1 + h * 128 + c);
        ss += w.x * a.x + w.y * a.y + w.z * a.z + w.w * a.w;
        sd += w.x * d.x + w.y * d.y + w.z * d.z + w.w * d.w;
    }
    As[k * 8 + h] = ss;
    Ad[k * 8 + h] = sd;
}

// ---------------- transpose W1 [128k][1024hc] -> W1bT [h][c][k] bf16 ------------

__global__ __launch_bounds__(256) void tr_w1(const float* __restrict__ W1,
                                             unsigned short* __restrict__ W1bT) {
    int kt = blockIdx.x & 3;          // 4 k-tiles of 32
    int hct = blockIdx.x >> 2;        // 32 hc-tiles of 32
    __shared__ unsigned short tile[32][33];
    int j = threadIdx.x & 31;
    int i0 = threadIdx.x >> 5;        // 0..7
    for (int i = i0; i < 32; i += 8)
        tile[i][j] = f2bf(W1[(size_t)(kt * 32 + i) * 1024 + hct * 32 + j]);
    __syncthreads();
    for (int i = i0; i < 32; i += 8) {
        int hc = hct * 32 + i, k = kt * 32 + j;
        int h = hc >> 7, c = hc & 127;
        W1bT[h * 16384 + c * 128 + k] = tile[j][i];
    }
}

// ---------------- transpose W2 [1024k][64c] -> W2bT [c][k] bf16 ------------------

__global__ __launch_bounds__(256) void tr_w2(const float* __restrict__ W2,
                                             unsigned short* __restrict__ W2bT) {
    int kt = blockIdx.x & 31;         // 32 k-tiles of 32
    int ctile = blockIdx.x >> 5;      // 2 c-tiles of 32
    __shared__ unsigned short tile[32][33];
    int j = threadIdx.x & 31;
    int i0 = threadIdx.x >> 5;
    for (int i = i0; i < 32; i += 8)
        tile[i][j] = f2bf(W2[(size_t)(kt * 32 + i) * 64 + ctile * 32 + j]);
    __syncthreads();
    for (int i = i0; i < 32; i += 8)
        W2bT[(size_t)(ctile * 32 + i) * 1024 + kt * 32 + j] = tile[j][i];
}

// ---------------- alpha1: as1/ad1 = x @ As / Ad  [N,8] ----------------

__global__ __launch_bounds__(256) void alpha1_kernel(
    const float* __restrict__ x, const float* __restrict__ As, const float* __restrict__ Ad,
    float* __restrict__ as1, float* __restrict__ ad1, int N) {
    __shared__ float sAs[1024], sAd[1024];
    int t = threadIdx.x;
    {
        int i = t * 4;
        *(float4*)(sAs + i) = *(const float4*)(As + i);
        *(float4*)(sAd + i) = *(const float4*)(Ad + i);
    }
    __syncthreads();
    int node = blockIdx.x * 32 + (t >> 3);
    int h = t & 7;
    if (node >= N) return;
    float accs = 0.f, accd = 0.f;
    for (int k = 0; k < 128; k += 4) {
        float4 xv = *(const float4*)(x + (size_t)node * 128 + k);
        accs += xv.x * sAs[k * 8 + h] + xv.y * sAs[(k + 1) * 8 + h]
              + xv.z * sAs[(k + 2) * 8 + h] + xv.w * sAs[(k + 3) * 8 + h];
        accd += xv.x * sAd[k * 8 + h] + xv.y * sAd[(k + 1) * 8 + h]
              + xv.z * sAd[(k + 2) * 8 + h] + xv.w * sAd[(k + 3) * 8 + h];
    }
    as1[node * 8 + h] = accs;
    ad1[node * 8 + h] = accd;
}

// ---------------- l1_aggx: y_b[n,h,:] = softmax-weighted sum of x[src,:], bf16 out ---

#define CHUNK 256

__global__ __launch_bounds__(256) void l1_aggx(
    const float* __restrict__ x, const float* __restrict__ as1, const float* __restrict__ ad1,
    const int* __restrict__ offsets, const int* __restrict__ srcs,
    unsigned short* __restrict__ y_b, int N) {
    int n = blockIdx.x;
    int t = threadIdx.x;
    int beg = offsets[n];
    int deg = offsets[n + 1] - beg;
    __shared__ int   ssrc[CHUNK];
    __shared__ float wsh[CHUNK * 8];
    __shared__ float ad[8], mh[8];
    __shared__ float red[256];
    if (t < 8) ad[t] = ad1[n * 8 + t];
    __syncthreads();
    // phase A: per-head max (8 heads x 32 edge-lanes)
    int h8 = t & 7, el = t >> 3;
    float m = -3.4e38f;
    for (int i = el; i < deg; i += 32) {
        int s = srcs[beg + i];
        m = fmaxf(m, leaky(as1[s * 8 + h8] + ad[h8]));
    }
    red[t] = m;
    __syncthreads();
    for (int off = 128; off >= 8; off >>= 1) {
        if (t < off) red[t] = fmaxf(red[t], red[t + off]);
        __syncthreads();
    }
    if (t < 8) mh[t] = red[t];
    __syncthreads();
    // phase B: chunked softmax-weight staging + x-row gather accumulate
    int h = t >> 5;
    int k0 = (t & 31) * 4;
    float ax = 0.f, ay = 0.f, az = 0.f, aw = 0.f, ssum = 0.f;
    for (int cb = 0; cb < deg; cb += CHUNK) {
        int cd = min(CHUNK, deg - cb);
        if (t < cd) ssrc[t] = srcs[beg + cb + t];
        __syncthreads();
        for (int idx = t; idx < cd * 8; idx += 256) {
            int i = idx >> 3, hx = idx & 7;
            int s = ssrc[i];
            wsh[idx] = __expf(leaky(as1[s * 8 + hx] + ad[hx]) - mh[hx]);
        }
        __syncthreads();
        int i = 0;
        for (; i + 1 < cd; i += 2) {
            int s0 = ssrc[i], s1 = ssrc[i + 1];
            float w0 = wsh[i * 8 + h], w1 = wsh[(i + 1) * 8 + h];
            float4 v0 = *(const float4*)(x + (size_t)s0 * 128 + k0);
            float4 v1 = *(const float4*)(x + (size_t)s1 * 128 + k0);
            ax = fmaf(w0, v0.x, ax); ay = fmaf(w0, v0.y, ay);
            az = fmaf(w0, v0.z, az); aw = fmaf(w0, v0.w, aw);
            ax = fmaf(w1, v1.x, ax); ay = fmaf(w1, v1.y, ay);
            az = fmaf(w1, v1.z, az); aw = fmaf(w1, v1.w, aw);
            ssum += w0 + w1;
        }
        if (i < cd) {
            int s0 = ssrc[i];
            float w0 = wsh[i * 8 + h];
            float4 v0 = *(const float4*)(x + (size_t)s0 * 128 + k0);
            ax = fmaf(w0, v0.x, ax); ay = fmaf(w0, v0.y, ay);
            az = fmaf(w0, v0.z, az); aw = fmaf(w0, v0.w, aw);
            ssum += w0;
        }
        __syncthreads();
    }
    float inv = 1.0f / (ssum + 1e-16f);
    ushort4 o;
    o.x = f2bf(ax * inv); o.y = f2bf(ay * inv);
    o.z = f2bf(az * inv); o.w = f2bf(aw * inv);
    *(ushort4*)(y_b + (size_t)n * 1024 + t * 4) = o;
}

// ---------------- l1_gemm (MFMA): hbuf_b = ELU(per-head y @ W1h + b1), bf16 out ----
// Block = (64-node tile, head). 4 waves x (16 nodes x 128 ch). No LDS.
// A-frag: y_b row 16B load; B-frag: W1bT [c][k] 16B load (L2 broadcast).

__global__ __launch_bounds__(256) void l1_gemm(
    const unsigned short* __restrict__ y_b, const unsigned short* __restrict__ W1bT,
    const float* __restrict__ b1, unsigned short* __restrict__ hbuf_b, int N) {
    int h  = blockIdx.x & 7;
    int nb = (blockIdx.x >> 3) * 64;
    int w  = threadIdx.x >> 6;
    int lane = threadIdx.x & 63;
    int n16 = lane & 15, quad = lane >> 4;
    int node_a = nb + w * 16 + n16;
    const unsigned short* yrow =
        y_b + (size_t)(node_a < N ? node_a : 0) * 1024 + h * 128 + quad * 8;
    const unsigned short* Wh = W1bT + h * 16384 + quad * 8;
    f32x4 acc[8];
#pragma unroll
    for (int ct = 0; ct < 8; ct++) acc[ct] = (f32x4){0.f, 0.f, 0.f, 0.f};
#pragma unroll
    for (int ks = 0; ks < 4; ks++) {
        bf16x8 a = *(const bf16x8*)(yrow + ks * 32);
#pragma unroll
        for (int ct = 0; ct < 8; ct++) {
            bf16x8 b = *(const bf16x8*)(Wh + (ct * 16 + n16) * 128 + ks * 32);
            acc[ct] = __builtin_amdgcn_mfma_f32_16x16x32_bf16(a, b, acc[ct], 0, 0, 0);
        }
    }
#pragma unroll
    for (int ct = 0; ct < 8; ct++) {
        int c = h * 128 + ct * 16 + n16;
        float bias = b1[c];
#pragma unroll
        for (int r = 0; r < 4; r++) {
            int node = nb + w * 16 + quad * 4 + r;
            if (node < N) {
                float v = acc[ct][r] + bias;
                v = v > 0.f ? v : expm1f(v);
                hbuf_b[(size_t)node * 1024 + c] = f2bf(v);
            }
        }
    }
}

// ---------------- l2_transform (MFMA): h2 = hbuf @ W2, alpha_s2/ad2 -----------------
// Block = 16 nodes; wave ct = col-tile (16 ch). K=1024. No GEMM LDS.

__global__ __launch_bounds__(256) void l2_transform(
    const unsigned short* __restrict__ hbuf_b, const unsigned short* __restrict__ W2bT,
    const float* __restrict__ a_src2, const float* __restrict__ a_dst2,
    float* __restrict__ h2, float* __restrict__ as2, float* __restrict__ ad2, int N) {
    int nb = blockIdx.x * 16;
    int ct = threadIdx.x >> 6;
    int lane = threadIdx.x & 63;
    int n16 = lane & 15, quad = lane >> 4;
    int node_a = nb + n16;
    const unsigned short* arow =
        hbuf_b + (size_t)(node_a < N ? node_a : N - 1) * 1024 + quad * 8;
    const unsigned short* brow = W2bT + (size_t)(ct * 16 + n16) * 1024 + quad * 8;
    f32x4 acc = (f32x4){0.f, 0.f, 0.f, 0.f};
#pragma unroll 8
    for (int ks = 0; ks < 32; ks++) {
        bf16x8 a = *(const bf16x8*)(arow + ks * 32);
        bf16x8 b = *(const bf16x8*)(brow + ks * 32);
        acc = __builtin_amdgcn_mfma_f32_16x16x32_bf16(a, b, acc, 0, 0, 0);
    }
    int c = ct * 16 + n16;
    float asc = a_src2[c], adc = a_dst2[c];
    float pav[4], pdv[4];
#pragma unroll
    for (int r = 0; r < 4; r++) {
        int node = nb + quad * 4 + r;
        if (node < N) h2[(size_t)node * 64 + c] = acc[r];
        pav[r] = acc[r] * asc;
        pdv[r] = acc[r] * adc;
#pragma unroll
        for (int mm = 1; mm <= 8; mm <<= 1) {   // reduce over n16 within quad-group
            pav[r] += __shfl_xor(pav[r], mm);
            pdv[r] += __shfl_xor(pdv[r], mm);
        }
    }
    __shared__ float sA[4][16], sD[4][16];
    if (n16 == 0) {
#pragma unroll
        for (int r = 0; r < 4; r++) {
            sA[ct][quad * 4 + r] = pav[r];
            sD[ct][quad * 4 + r] = pdv[r];
        }
    }
    __syncthreads();
    if (threadIdx.x < 16) {
        int node = nb + threadIdx.x;
        if (node < N) {
            as2[node] = sA[0][threadIdx.x] + sA[1][threadIdx.x] + sA[2][threadIdx.x] + sA[3][threadIdx.x];
            ad2[node] = sD[0][threadIdx.x] + sD[1][threadIdx.x] + sD[2][threadIdx.x] + sD[3][threadIdx.x];
        }
    }
}

// ---------------- Layer 2 aggregate ----------------

__global__ __launch_bounds__(256) void l2_agg(
    const float* __restrict__ h2, const float* __restrict__ as2, const float* __restrict__ ad2,
    const float* __restrict__ b2, const int* __restrict__ offsets, const int* __restrict__ srcs,
    float* __restrict__ out, int N) {
    int n = blockIdx.x;
    int t = threadIdx.x;
    int beg = offsets[n];
    int deg = offsets[n + 1] - beg;
    __shared__ int   ssrc[CHUNK];
    __shared__ float wsh[CHUNK];
    __shared__ float red[256];
    __shared__ float m_sh, s_sh;
    float adn = ad2[n];
    float m = -3.4e38f;
    for (int i = t; i < deg; i += 256) m = fmaxf(m, leaky(as2[srcs[beg + i]] + adn));
    red[t] = m;
    __syncthreads();
    for (int off = 128; off >= 1; off >>= 1) {
        if (t < off) red[t] = fmaxf(red[t], red[t + off]);
        __syncthreads();
    }
    if (t == 0) m_sh = red[0];
    __syncthreads();
    float mv = m_sh;
    int c = t & 63, eg = t >> 6;
    float acc = 0.f, wpart = 0.f;
    for (int cb = 0; cb < deg; cb += CHUNK) {
        int cd = min(CHUNK, deg - cb);
        if (t < cd) {
            int s = srcs[beg + cb + t];
            ssrc[t] = s;
            float w = __expf(leaky(as2[s] + adn) - mv);
            wsh[t] = w;
            wpart += w;
        }
        __syncthreads();
        for (int i = eg; i < cd; i += 4)
            acc = fmaf(wsh[i], h2[(size_t)ssrc[i] * 64 + c], acc);
        __syncthreads();
    }
    red[t] = wpart;
    __syncthreads();
    for (int off = 128; off >= 1; off >>= 1) {
        if (t < off) red[t] += red[t + off];
        __syncthreads();
    }
    if (t == 0) s_sh = red[0] + 1e-16f;
    __syncthreads();
    float stot = s_sh;
    red[t] = acc;
    __syncthreads();
    if (t < 128) red[t] += red[t + 128];
    __syncthreads();
    if (t < 64) {
        float v = red[t] + red[t + 64];
        out[(size_t)n * 64 + t] = v / stot + b2[t];
    }
}

// ---------------- launch ----------------

static inline size_t align_up(size_t v, size_t a) { return (v + a - 1) / a * a; }

extern "C" void kernel_launch(void* const* d_in, const int* in_sizes, int n_in,
                              void* d_out, int out_size, void* d_ws, size_t ws_size,
                              hipStream_t stream) {
    const float* x      = (const float*)d_in[0];
    const int*   ei     = (const int*)d_in[1];
    const float* W1     = (const float*)d_in[2];
    const float* a_src1 = (const float*)d_in[3];
    const float* a_dst1 = (const float*)d_in[4];
    const float* b1     = (const float*)d_in[5];
    const float* W2     = (const float*)d_in[6];
    const float* a_src2 = (const float*)d_in[7];
    const float* a_dst2 = (const float*)d_in[8];
    const float* b2     = (const float*)d_in[9];
    float* out = (float*)d_out;

    int N = in_sizes[0] / 128;
    int E = in_sizes[1] / 2;
    int M = E + N;

    char* p = (char*)d_ws;
    size_t off = 0;
    auto carve = [&](size_t bytes) {
        void* r = p + off;
        off = align_up(off + bytes, 256);
        return r;
    };
    int*            counts  = (int*)carve((size_t)N * 4);
    int*            offsets = (int*)carve((size_t)(N + 1) * 4);
    int*            cursor  = (int*)carve((size_t)N * 4);
    int*            srcs    = (int*)carve((size_t)M * 4);
    float*          As      = (float*)carve(1024 * 4);
    float*          Ad      = (float*)carve(1024 * 4);
    float*          as1     = (float*)carve((size_t)N * 8 * 4);
    float*          ad1     = (float*)carve((size_t)N * 8 * 4);
    float*          as2     = (float*)carve((size_t)N * 4);
    float*          ad2     = (float*)carve((size_t)N * 4);
    float*          h2      = (float*)carve((size_t)N * 64 * 4);
    unsigned short* W1bT    = (unsigned short*)carve((size_t)8 * 128 * 128 * 2);
    unsigned short* W2bT    = (unsigned short*)carve((size_t)64 * 1024 * 2);
    unsigned short* y_b     = (unsigned short*)carve((size_t)N * 1024 * 2);
    unsigned short* hbuf_b  = (unsigned short*)carve((size_t)N * 1024 * 2);
    (void)ws_size; // ~47 MB

    hipMemsetAsync(counts, 0, (size_t)N * 4, stream);
    prep_kernel<<<4, 256, 0, stream>>>(W1, a_src1, a_dst1, As, Ad);
    tr_w1<<<128, 256, 0, stream>>>(W1, W1bT);
    tr_w2<<<64, 256, 0, stream>>>(W2, W2bT);
    alpha1_kernel<<<(N + 31) / 32, 256, 0, stream>>>(x, As, Ad, as1, ad1, N);
    count_kernel<<<(M + 255) / 256, 256, 0, stream>>>(ei, counts, E, N);
    scan_kernel<<<1, 1024, 0, stream>>>(counts, offsets, cursor, N);
    fill_kernel<<<(M + 255) / 256, 256, 0, stream>>>(ei, cursor, srcs, E, N);
    l1_aggx<<<N, 256, 0, stream>>>(x, as1, ad1, offsets, srcs, y_b, N);
    l1_gemm<<<((N + 63) / 64) * 8, 256, 0, stream>>>(y_b, W1bT, b1, hbuf_b, N);
    l2_transform<<<(N + 15) / 16, 256, 0, stream>>>(hbuf_b, W2bT, a_src2, a_dst2, h2, as2, ad2, N);
    l2_agg<<<N, 256, 0, stream>>>(h2, as2, ad2, b2, offsets, srcs, out, N);
}